// Round 8
// baseline (199.385 us; speedup 1.0000x reference)
//
#include <hip/hip_runtime.h>
#include <hip/hip_bf16.h>
#include <math.h>

#define BSZ 4
#define CK 80
#define CX1 64
#define CGT 40
#define HH 64
#define WWI 64
#define HWSZ 4096
#define NGRP 5
#define EPSV 1e-5f
#define SPLIT 8
#define KPB (HWSZ / SPLIT)  // 512 keys per block
#define NCH (KPB / 32)      // 16 chunks
#define PADHW 4356          // 66*66

typedef short bf16x8 __attribute__((ext_vector_type(8)));
typedef float f32x16 __attribute__((ext_vector_type(16)));
#define MFMA32(a, b, c) __builtin_amdgcn_mfma_f32_32x32x16_bf16(a, b, c, 0, 0, 0)

__device__ __forceinline__ float sigmoidf_(float x) { return 1.f / (1.f + __expf(-x)); }
__device__ __forceinline__ float siluf_(float x) { return x * sigmoidf_(x); }

__device__ __forceinline__ ushort f2bf(float x) {
  union { float f; uint u; } c;
  c.f = x;
  uint u = c.u;
  return (ushort)((u + 0x7FFFu + ((u >> 16) & 1u)) >> 16);
}
__device__ __forceinline__ uint pack2bf(float lo, float hi) {
  return (uint)f2bf(lo) | ((uint)f2bf(hi) << 16);
}
__device__ __forceinline__ float bf2f(ushort u) {
  union { uint u; float f; } c;
  c.u = ((uint)u) << 16;
  return c.f;
}
__device__ __forceinline__ bf16x8 as_bf8(uint4 v) {
  union { uint4 u; bf16x8 b; } c;
  c.u = v;
  return c.b;
}

// ================= setup: all weight repacks + all pad-border zeroes, 1 launch ========
// repack segments (wt[tap*COP*CIN + co*CIN + ci] = w[(co*CIN+ci)*TAPS + tap]):
//  [0,55296)        wp1t 80,64,9,96
//  [55296,62976)    widt 80,80,1,96
//  [62976,109056)   wg1t 40,80,9,64
//  [109056,178176)  wh1t 80,80,9,96
// zero segments (uint writes at border positions):
//  [178176,211456)  x1_tm  (CIN=64 -> 32 uints/pos)
//  [211456,253056)  x2_tm  (40 uints/pos)
//  [253056,294656)  ym_tm  (40 uints/pos)
__device__ __forceinline__ void repack_one(const float* w, ushort* wt, int idx, int COUT,
                                           int CIN, int TAPS, int COP) {
  int tap = idx / (COP * CIN);
  int rem = idx - tap * COP * CIN;
  int co = rem / CIN, ci = rem - co * CIN;
  float v = (co < COUT) ? w[((size_t)co * CIN + ci) * TAPS + tap] : 0.f;
  wt[idx] = f2bf(v);
}
__device__ __forceinline__ void zero_one(ushort* buf, int u, int cin) {
  int nu = cin >> 1;
  int pid = u / nu, uoff = u - pid * nu;
  int b = pid / 260, pos = pid - b * 260;
  int h, w;
  if (pos < 66) { h = 0; w = pos; }
  else if (pos < 132) { h = 65; w = pos - 66; }
  else if (pos < 196) { h = pos - 131; w = 0; }
  else { h = pos - 195; w = 65; }
  ((uint*)(buf + (((size_t)b * PADHW) + h * 66 + w) * cin))[uoff] = 0;
}
__global__ __launch_bounds__(256) void setup_k(const float* __restrict__ w_p1,
                                               const float* __restrict__ w_id,
                                               const float* __restrict__ wg1,
                                               const float* __restrict__ wh1,
                                               ushort* wp1t, ushort* widt, ushort* wg1t,
                                               ushort* wh1t, ushort* x1_tm, ushort* x2_tm,
                                               ushort* ym_tm) {
  int idx = blockIdx.x * 256 + threadIdx.x;
  if (idx < 55296) repack_one(w_p1, wp1t, idx, 80, 64, 9, 96);
  else if (idx < 62976) repack_one(w_id, widt, idx - 55296, 80, 80, 1, 96);
  else if (idx < 109056) repack_one(wg1, wg1t, idx - 62976, 40, 80, 9, 64);
  else if (idx < 178176) repack_one(wh1, wh1t, idx - 109056, 80, 80, 9, 96);
  else if (idx < 211456) zero_one(x1_tm, idx - 178176, CX1);
  else if (idx < 253056) zero_one(x2_tm, idx - 211456, CK);
  else if (idx < 294656) zero_one(ym_tm, idx - 253056, CK);
}

// ================= stage: NCHW f32 -> padded token-major bf16, both inputs, 1 launch ===
template <int CIN>
__device__ __forceinline__ void stage_body(const float* __restrict__ in,
                                           ushort* __restrict__ xtm,
                                           float (*tile)[81]) {
  int h = blockIdx.x, b = blockIdx.y;
  int w = threadIdx.x & 63, cio = threadIdx.x >> 6;
  for (int ci = cio; ci < CIN; ci += 4)
    tile[w][ci] = in[((size_t)(b * CIN + ci)) * HWSZ + h * 64 + w];
  __syncthreads();
  const int PAIRS = CIN / 2;
  for (int idx = threadIdx.x; idx < 64 * PAIRS; idx += 256) {
    int wi = idx / PAIRS, cp = idx - wi * PAIRS;
    uint pk = pack2bf(tile[wi][2 * cp], tile[wi][2 * cp + 1]);
    *(uint*)(&xtm[(((size_t)b * PADHW) + (h + 1) * 66 + (wi + 1)) * CIN + 2 * cp]) = pk;
  }
}
__global__ __launch_bounds__(256) void stage2_k(const float* __restrict__ x1,
                                                const float* __restrict__ x2,
                                                ushort* __restrict__ x1_tm,
                                                ushort* __restrict__ x2_tm) {
  __shared__ float tile[64][81];
  if (blockIdx.z == 0) stage_body<CX1>(x1, x1_tm, tile);
  else stage_body<CK>(x2, x2_tm, tile);
}

// ================= implicit-GEMM MFMA conv body =================
template <int CIN, int COP, int TAPS, int COUT>
__device__ __forceinline__ void conv_body(const ushort* __restrict__ xtm,
                                          const ushort* __restrict__ wt,
                                          float* __restrict__ out, int tile, int nt,
                                          float* lds) {
  int lane = threadIdx.x;
  int half = lane >> 5, lq = lane & 31;
  int b = tile >> 7;
  int tstart = (tile & 127) * 32;
  int h = tstart >> 6, w0 = tstart & 63;
  int p0 = (h + 1) * 66 + (w0 + lq + 1);
  const ushort* xb = xtm + ((size_t)b * PADHW) * CIN;
  const ushort* wbase = wt + ((size_t)(nt * 32 + lq)) * CIN + half * 8;
  f32x16 acc;
#pragma unroll
  for (int i = 0; i < 16; ++i) acc[i] = 0.f;
#pragma unroll 3
  for (int tap = 0; tap < TAPS; ++tap) {
    int dtap = (TAPS == 1) ? 0 : ((tap / 3) - 1) * 66 + (tap % 3) - 1;
    const ushort* ap = xb + (size_t)(p0 + dtap) * CIN + half * 8;
    const ushort* wp = wbase + (size_t)tap * COP * CIN;
#pragma unroll
    for (int kc = 0; kc < CIN / 16; ++kc) {
      bf16x8 A = *(const bf16x8*)(ap + kc * 16);
      bf16x8 Bf = *(const bf16x8*)(wp + kc * 16);
      acc = MFMA32(A, Bf, acc);
    }
  }
#pragma unroll
  for (int r = 0; r < 16; ++r) {
    int m = (r & 3) + 8 * (r >> 2) + 4 * half;
    lds[m * 33 + lq] = acc[r];
  }
  __syncthreads();
#pragma unroll
  for (int i = 0; i < 16; ++i) {
    int idx = i * 64 + lane;
    int c2 = idx >> 5, m2 = idx & 31;
    int co = nt * 32 + c2;
    if (co < COUT) out[((size_t)b * COUT + co) * HWSZ + tstart + m2] = lds[m2 * 33 + c2];
  }
}

// fused: 3 independent convs (c1, xid, cg1) in one grid
__global__ __launch_bounds__(64) void convA_k(const ushort* __restrict__ x1_tm,
                                              const ushort* __restrict__ x2_tm,
                                              const ushort* __restrict__ wp1t,
                                              const ushort* __restrict__ widt,
                                              const ushort* __restrict__ wg1t,
                                              float* __restrict__ c1,
                                              float* __restrict__ xid,
                                              float* __restrict__ cg1) {
  __shared__ float lds[32 * 33];
  int zy = blockIdx.y;
  if (zy < 3) conv_body<CX1, 96, 9, CK>(x1_tm, wp1t, c1, blockIdx.x, zy, lds);
  else if (zy < 6) conv_body<CK, 96, 1, CK>(x2_tm, widt, xid, blockIdx.x, zy - 3, lds);
  else conv_body<CK, 64, 9, CGT>(x2_tm, wg1t, cg1, blockIdx.x, zy - 6, lds);
}

// head conv (separate: depends on post2)
__global__ __launch_bounds__(64) void convH_k(const ushort* __restrict__ ym_tm,
                                              const ushort* __restrict__ wh1t,
                                              float* __restrict__ ch1) {
  __shared__ float lds[32 * 33];
  conv_body<CK, 96, 9, CK>(ym_tm, wh1t, ch1, blockIdx.x, blockIdx.y, lds);
}

// ================= GroupNorm partial sums =================
__device__ __forceinline__ void gn_part_body(const float* __restrict__ x,
                                             float* __restrict__ pstat, int C, int cpg) {
  int bg = blockIdx.x;
  int sl = blockIdx.y;
  int g = bg % NGRP, b = bg / NGRP;
  int npb = cpg * HWSZ / 16;
  const float4* p =
      (const float4*)(x + ((size_t)b * C + (size_t)g * cpg) * HWSZ + (size_t)sl * npb);
  int n4 = npb / 4;
  float s = 0.f, s2 = 0.f;
  for (int i = threadIdx.x; i < n4; i += 256) {
    float4 v = p[i];
    s += v.x + v.y + v.z + v.w;
    s2 += v.x * v.x + v.y * v.y + v.z * v.z + v.w * v.w;
  }
#pragma unroll
  for (int off = 32; off; off >>= 1) {
    s += __shfl_down(s, off);
    s2 += __shfl_down(s2, off);
  }
  __shared__ float sh[4][2];
  int wave = threadIdx.x >> 6;
  if ((threadIdx.x & 63) == 0) {
    sh[wave][0] = s;
    sh[wave][1] = s2;
  }
  __syncthreads();
  if (threadIdx.x == 0) {
    pstat[bg * 32 + sl * 2] = sh[0][0] + sh[1][0] + sh[2][0] + sh[3][0];
    pstat[bg * 32 + sl * 2 + 1] = sh[0][1] + sh[1][1] + sh[2][1] + sh[3][1];
  }
}
__global__ __launch_bounds__(256) void gnA_k(const float* __restrict__ c1,
                                             const float* __restrict__ xid,
                                             const float* __restrict__ cg1,
                                             float* __restrict__ pst1,
                                             float* __restrict__ pstid,
                                             float* __restrict__ pstg) {
  int z = blockIdx.z;
  if (z == 0) gn_part_body(c1, pst1, CK, 16);
  else if (z == 1) gn_part_body(xid, pstid, CK, 16);
  else gn_part_body(cg1, pstg, CGT, 8);
}
__global__ __launch_bounds__(256) void gnH_k(const float* __restrict__ ch1,
                                             float* __restrict__ psth) {
  gn_part_body(ch1, psth, CK, 16);
}

// inline finalize: threads 0..NGRP-1 fill LDS stats, caller must sync after
__device__ __forceinline__ void gn_fin_lds(const float* __restrict__ ps, int b, float invn,
                                           int tid, float* gsm, float* gsr) {
  if (tid < NGRP) {
    const float* p = ps + ((size_t)(b * NGRP + tid)) * 32;
    float s = 0.f, s2 = 0.f;
#pragma unroll
    for (int sl = 0; sl < 16; ++sl) {
      s += p[sl * 2];
      s2 += p[sl * 2 + 1];
    }
    float m = s * invn;
    gsm[tid] = m;
    gsr[tid] = rsqrtf(fmaxf(s2 * invn - m * m, 0.f) + EPSV);
  }
}

// ================= fused token transforms: z=0 x1->q ; z=1 x2->(k, gated v^T) ==========
__global__ __launch_bounds__(512) void qkv_k(const float* __restrict__ c1,
                                             const float* __restrict__ x2,
                                             const float* __restrict__ cg1,
                                             const float* __restrict__ pst1,
                                             const float* __restrict__ pstg,
                                             const float* __restrict__ gn1_g,
                                             const float* __restrict__ gn1_b,
                                             const float* __restrict__ gng_g,
                                             const float* __restrict__ gng_b,
                                             const float* __restrict__ lnx1_g,
                                             const float* __restrict__ lnx1_b,
                                             const float* __restrict__ lnx2_g,
                                             const float* __restrict__ lnx2_b,
                                             const float* __restrict__ wq,
                                             const float* __restrict__ wk,
                                             const float* __restrict__ wv,
                                             const float* __restrict__ wg2,
                                             const float* __restrict__ bg2,
                                             ushort* __restrict__ qb,
                                             ushort* __restrict__ kb,
                                             ushort* __restrict__ vt) {
  __shared__ float xs[64][85];
  __shared__ float xs2[64][45];
  __shared__ float mrs[64][2];
  __shared__ float gsm[NGRP], gsr[NGRP];
  int tid = threadIdx.x, tl = tid & 63, g = tid >> 6;
  int b = blockIdx.y, n0 = blockIdx.x * 64;

  if (blockIdx.z == 0) {
    // ---- x1 -> q ----
    gn_fin_lds(pst1, b, 1.f / (16 * HWSZ), tid, gsm, gsr);
    __syncthreads();
#pragma unroll
    for (int j = 0; j < 10; ++j) {
      int c = g * 10 + j;
      int gr = c >> 4;
      float v = (c1[((size_t)(b * CK + c)) * HWSZ + n0 + tl] - gsm[gr]) * gsr[gr] * gn1_g[c] +
                gn1_b[c];
      xs[tl][c] = siluf_(v);
    }
    __syncthreads();
    if (tid < 64) {
      float s = 0.f, s2 = 0.f;
#pragma unroll
      for (int c = 0; c < CK; ++c) {
        float v = xs[tid][c];
        s += v;
        s2 += v * v;
      }
      float mean = s * (1.f / CK);
      float var = s2 * (1.f / CK) - mean * mean;
      mrs[tid][0] = mean;
      mrs[tid][1] = rsqrtf(var + EPSV);
    }
    __syncthreads();
    float x[CK];
    float mean = mrs[tl][0], rstd = mrs[tl][1];
#pragma unroll
    for (int c = 0; c < CK; ++c) x[c] = (xs[tl][c] - mean) * rstd * lnx1_g[c] + lnx1_b[c];
    ushort* qp = qb + ((size_t)(b * HWSZ) + n0 + tl) * CK;
    const float sc = 0.111803398874989485f;  // 1/sqrt(80)
    for (int j = 0; j < 10; j += 2) {
      int o = g * 10 + j;
      float a0 = 0.f, a1 = 0.f;
      const float* w0 = wq + (size_t)o * CK;
      const float* w1 = w0 + CK;
#pragma unroll
      for (int k = 0; k < CK; ++k) {
        a0 += x[k] * w0[k];
        a1 += x[k] * w1[k];
      }
      *(uint*)(qp + o) = pack2bf(a0 * sc, a1 * sc);
    }
  } else {
    // ---- x2 -> k, gated v^T ----
    gn_fin_lds(pstg, b, 1.f / (8 * HWSZ), tid, gsm, gsr);
#pragma unroll
    for (int j = 0; j < 10; ++j) {
      int c = g * 10 + j;
      xs[tl][c] = x2[((size_t)(b * CK + c)) * HWSZ + n0 + tl];
    }
    __syncthreads();
#pragma unroll
    for (int j = 0; j < 5; ++j) {
      int c = g * 5 + j;
      int gr = c >> 3;
      float v =
          (cg1[((size_t)(b * CGT + c)) * HWSZ + n0 + tl] - gsm[gr]) * gsr[gr] * gng_g[c] +
          gng_b[c];
      xs2[tl][c] = siluf_(v);
    }
    if (tid < 64) {
      float s = 0.f, s2 = 0.f;
#pragma unroll
      for (int c = 0; c < CK; ++c) {
        float v = xs[tid][c];
        s += v;
        s2 += v * v;
      }
      float mean = s * (1.f / CK);
      float var = s2 * (1.f / CK) - mean * mean;
      mrs[tid][0] = mean;
      mrs[tid][1] = rsqrtf(var + EPSV);
    }
    __syncthreads();
    float x[CK];
    float mean = mrs[tl][0], rstd = mrs[tl][1];
#pragma unroll
    for (int c = 0; c < CK; ++c) x[c] = (xs[tl][c] - mean) * rstd * lnx2_g[c] + lnx2_b[c];
    float xg[CGT];
#pragma unroll
    for (int c = 0; c < CGT; ++c) xg[c] = xs2[tl][c];
    ushort* kp = kb + ((size_t)(b * HWSZ) + n0 + tl) * CK;
    for (int j = 0; j < 10; j += 2) {
      int o = g * 10 + j;
      float aK0 = 0.f, aK1 = 0.f, aV0 = 0.f, aV1 = 0.f;
      const float* wk0 = wk + (size_t)o * CK;
      const float* wk1 = wk0 + CK;
      const float* wv0 = wv + (size_t)o * CK;
      const float* wv1 = wv0 + CK;
#pragma unroll
      for (int k = 0; k < CK; ++k) {
        float xv = x[k];
        aK0 += xv * wk0[k];
        aK1 += xv * wk1[k];
        aV0 += xv * wv0[k];
        aV1 += xv * wv1[k];
      }
      *(uint*)(kp + o) = pack2bf(aK0, aK1);
      float g0 = bg2[o], g1 = bg2[o + 1];
      const float* wgp0 = wg2 + (size_t)o * CGT;
      const float* wgp1 = wgp0 + CGT;
#pragma unroll
      for (int k = 0; k < CGT; ++k) {
        g0 += xg[k] * wgp0[k];
        g1 += xg[k] * wgp1[k];
      }
      vt[((size_t)(b * 96 + o)) * HWSZ + n0 + tl] =
          f2bf(aV0 * (1.f + 0.1f * sigmoidf_(g0)));
      vt[((size_t)(b * 96 + o + 1)) * HWSZ + n0 + tl] =
          f2bf(aV1 * (1.f + 0.1f * sigmoidf_(g1)));
    }
#pragma unroll
    for (int rr = 0; rr < 2; ++rr) {
      int r = CK + g * 2 + rr;
      vt[((size_t)(b * 96 + r)) * HWSZ + n0 + tl] = 0;
    }
  }
}

// ================= MFMA attention: 8 waves, async-split staging, bf16 partials =========
__global__ __launch_bounds__(512) void attn2_k(const ushort* __restrict__ qb,
                                               const ushort* __restrict__ kb,
                                               const ushort* __restrict__ vt,
                                               ushort* __restrict__ part_o,
                                               float* __restrict__ part_l) {
  __shared__ ushort kl[2][2816];  // 32 tok x 88ch(pad)
  __shared__ ushort vl[2][3456];  // 96 d x 36keys(pad)
  int tid = threadIdx.x, wid = tid >> 6, lane = tid & 63;
  int half = lane >> 5, lq = lane & 31;
  int qblk = blockIdx.x, b = blockIdx.y, ks = blockIdx.z;
  int k00 = ks * KPB;

  const ushort* qp =
      qb + ((size_t)b * HWSZ + qblk * 256 + wid * 32 + lq) * CK + half * 8;
  bf16x8 qf0 = *(const bf16x8*)(qp);
  bf16x8 qf1 = *(const bf16x8*)(qp + 16);
  bf16x8 qf2 = *(const bf16x8*)(qp + 32);
  bf16x8 qf3 = *(const bf16x8*)(qp + 48);
  bf16x8 qf4 = *(const bf16x8*)(qp + 64);

  f32x16 oa[3];
#pragma unroll
  for (int dt = 0; dt < 3; ++dt)
#pragma unroll
    for (int i = 0; i < 16; ++i) oa[dt][i] = 0.f;
  float lsum = 0.f;

  const ushort* kgb = kb + (size_t)b * HWSZ * CK;
  const ushort* vgb = vt + (size_t)b * 96 * HWSZ;

  uint4 kreg;
  uint2 vreg0, vreg1;
  int ktok = tid / 10, kgc = tid - ktok * 10;  // tid<320 only
  int vr0 = tid >> 3, vgc0 = tid & 7;
  int vr1 = (512 + tid) >> 3, vgc1 = tid & 7;

  auto load_stage = [&](int ch) {
    int k0 = k00 + ch * 32;
    const ushort* kg = kgb + (size_t)k0 * CK;
    if (tid < 320) kreg = *(const uint4*)(kg + (size_t)ktok * CK + kgc * 8);
    vreg0 = *(const uint2*)(vgb + (size_t)vr0 * HWSZ + k0 + vgc0 * 4);
    if (tid < 256) vreg1 = *(const uint2*)(vgb + (size_t)vr1 * HWSZ + k0 + vgc1 * 4);
  };
  auto write_stage = [&](int buf) {
    if (tid < 320) *(uint4*)(&kl[buf][ktok * 88 + kgc * 8]) = kreg;
    *(uint2*)(&vl[buf][vr0 * 36 + vgc0 * 4]) = vreg0;
    if (tid < 256) *(uint2*)(&vl[buf][vr1 * 36 + vgc1 * 4]) = vreg1;
  };

  load_stage(0);
  write_stage(0);
  __syncthreads();

  for (int c = 0; c < NCH; ++c) {
    int cur = c & 1;
    if (c + 1 < NCH) load_stage(c + 1);

    const ushort* klp = &kl[cur][lq * 88 + half * 8];
    f32x16 s;
#pragma unroll
    for (int i = 0; i < 16; ++i) s[i] = 0.f;
    s = MFMA32(*(const bf16x8*)(klp), qf0, s);
    s = MFMA32(*(const bf16x8*)(klp + 16), qf1, s);
    s = MFMA32(*(const bf16x8*)(klp + 32), qf2, s);
    s = MFMA32(*(const bf16x8*)(klp + 48), qf3, s);
    s = MFMA32(*(const bf16x8*)(klp + 64), qf4, s);

    uint w[8];
#pragma unroll
    for (int i = 0; i < 8; ++i) {
      float e0 = __expf(s[2 * i]);
      float e1 = __expf(s[2 * i + 1]);
      lsum += e0 + e1;
      __hip_bfloat162 t = __float22bfloat162_rn(make_float2(e0, e1));
      union { __hip_bfloat162 h; uint u; } cv;
      cv.h = t;
      w[i] = cv.u;
    }
    uint4 pw0 = make_uint4(w[0], w[1], w[2], w[3]);
    uint4 pw1 = make_uint4(w[4], w[5], w[6], w[7]);

#pragma unroll
    for (int dt = 0; dt < 3; ++dt) {
      const ushort* vp = &vl[cur][(dt * 32 + lq) * 36 + half * 4];
      uint2 a0 = *(const uint2*)(vp);
      uint2 b0 = *(const uint2*)(vp + 8);
      uint2 a1 = *(const uint2*)(vp + 16);
      uint2 b1 = *(const uint2*)(vp + 24);
      oa[dt] = MFMA32(as_bf8(make_uint4(a0.x, a0.y, b0.x, b0.y)), as_bf8(pw0), oa[dt]);
      oa[dt] = MFMA32(as_bf8(make_uint4(a1.x, a1.y, b1.x, b1.y)), as_bf8(pw1), oa[dt]);
    }
    if (c + 1 < NCH) write_stage(cur ^ 1);
    __syncthreads();
  }

  float ltot = lsum + __shfl_xor(lsum, 32);
  size_t tileidx = (size_t)((b * 128 + qblk * 8 + wid) * SPLIT + ks);
  ushort* po = part_o + tileidx * 2560;
#pragma unroll
  for (int dt = 0; dt < 3; ++dt)
#pragma unroll
    for (int r = 0; r < 16; ++r) {
      int d = dt * 32 + (r & 3) + 8 * (r >> 2) + 4 * half;
      if (d < CK) po[d * 32 + lq] = f2bf(oa[dt][r]);
    }
  if (lane < 32) part_l[tileidx * 32 + lq] = ltot;
}

// ================= post2: merge partials + residual GN + LN -> padded bf16 map =========
__global__ __launch_bounds__(512) void post2_k(const ushort* __restrict__ part_o,
                                               const float* __restrict__ part_l,
                                               const float* __restrict__ xid,
                                               const float* __restrict__ pstid,
                                               const float* __restrict__ gg,
                                               const float* __restrict__ gb,
                                               const float* __restrict__ lg,
                                               const float* __restrict__ lb,
                                               ushort* __restrict__ ym_tm) {
  __shared__ float xs[64][85];
  __shared__ float mrs[64][2];
  __shared__ float gsm[NGRP], gsr[NGRP];
  __shared__ float invl[64];
  int tid = threadIdx.x, tl = tid & 63, g = tid >> 6;
  int b = blockIdx.y, n0 = blockIdx.x * 64;
  gn_fin_lds(pstid, b, 1.f / (16 * HWSZ), tid, gsm, gsr);
  if (tid < 64) {
    int token = n0 + tid;
    int qt = token >> 5, lqq = token & 31;
    size_t tb = (size_t)(b * 128 + qt) * SPLIT;
    float s = 0.f;
#pragma unroll
    for (int sp = 0; sp < SPLIT; ++sp) s += part_l[(tb + sp) * 32 + lqq];
    invl[tid] = 1.f / s;
  }
  __syncthreads();
  {
    int token = n0 + tl;
    int qt = token >> 5, lqq = token & 31;
    size_t tb = (size_t)(b * 128 + qt) * SPLIT;
    float il = invl[tl];
#pragma unroll
    for (int j = 0; j < 10; ++j) {
      int c = g * 10 + j;
      int gr = c >> 4;
      float y = 0.f;
#pragma unroll
      for (int sp = 0; sp < SPLIT; ++sp)
        y += bf2f(part_o[(tb + sp) * 2560 + c * 32 + lqq]);
      y *= il;
      xs[tl][c] = y + ((xid[((size_t)(b * CK + c)) * HWSZ + n0 + tl] - gsm[gr]) * gsr[gr] *
                           gg[c] +
                       gb[c]);
    }
  }
  __syncthreads();
  if (tid < 64) {
    float s = 0.f, s2 = 0.f;
#pragma unroll
    for (int c = 0; c < CK; ++c) {
      float v = xs[tid][c];
      s += v;
      s2 += v * v;
    }
    float mean = s * (1.f / CK);
    float var = s2 * (1.f / CK) - mean * mean;
    mrs[tid][0] = mean;
    mrs[tid][1] = rsqrtf(var + EPSV);
  }
  __syncthreads();
  float mean = mrs[tl][0], rstd = mrs[tl][1];
#pragma unroll
  for (int j = 0; j < 10; ++j) {
    int c = g * 10 + j;
    xs[tl][c] = (xs[tl][c] - mean) * rstd * lg[c] + lb[c];
  }
  __syncthreads();
  int hh = n0 >> 6;
  ushort* op = ym_tm + (((size_t)b * PADHW) + (hh + 1) * 66 + 1) * CK;
  for (int idx = tid; idx < 640; idx += 512) {
    int w = idx / 10, q4 = idx - w * 10;
    const float* xp = &xs[w][q4 * 8];
    uint4 pk;
    pk.x = pack2bf(xp[0], xp[1]);
    pk.y = pack2bf(xp[2], xp[3]);
    pk.z = pack2bf(xp[4], xp[5]);
    pk.w = pack2bf(xp[6], xp[7]);
    *(uint4*)(op + (size_t)w * CK + q4 * 8) = pk;
  }
}

// ================= head final =================
__global__ __launch_bounds__(512) void final_k(const float* __restrict__ ch1,
                                               const float* __restrict__ psth,
                                               const float* __restrict__ gg,
                                               const float* __restrict__ gb,
                                               const float* __restrict__ wh2,
                                               const float* __restrict__ bh2,
                                               const float* __restrict__ x2,
                                               float* __restrict__ out) {
  __shared__ float pd[64][9];
  __shared__ float pm[64][9];
  __shared__ float gsm[NGRP], gsr[NGRP];
  int tid = threadIdx.x, tl = tid & 63, g = tid >> 6;
  int b = blockIdx.y, n0 = blockIdx.x * 64;
  gn_fin_lds(psth, b, 1.f / (16 * HWSZ), tid, gsm, gsr);
  __syncthreads();
  float acc = 0.f, mn = 3.4e38f;
#pragma unroll
  for (int j = 0; j < 10; ++j) {
    int c = g * 10 + j;
    int gr = c >> 4;
    float v = (ch1[((size_t)(b * CK + c)) * HWSZ + n0 + tl] - gsm[gr]) * gsr[gr] * gg[c] +
              gb[c];
    acc += siluf_(v) * wh2[c];
    mn = fminf(mn, x2[((size_t)(b * CK + c)) * HWSZ + n0 + tl]);
  }
  pd[tl][g] = acc;
  pm[tl][g] = mn;
  __syncthreads();
  if (tid < 64) {
    float a = bh2[0];
    float m = pm[tid][0];
#pragma unroll
    for (int g2 = 0; g2 < 8; ++g2) a += pd[tid][g2];
#pragma unroll
    for (int g2 = 1; g2 < 8; ++g2) m = fminf(m, pm[tid][g2]);
    out[(size_t)b * HWSZ + n0 + tid] = sigmoidf_(a);
    out[(size_t)BSZ * HWSZ + (size_t)b * HWSZ + n0 + tid] = m;
  }
}

extern "C" void kernel_launch(void* const* d_in, const int* in_sizes, int n_in,
                              void* d_out, int out_size, void* d_ws, size_t ws_size,
                              hipStream_t stream) {
  const float* x1 = (const float*)d_in[0];
  const float* x2 = (const float*)d_in[1];
  const float* w_p1 = (const float*)d_in[2];
  const float* gn1_g = (const float*)d_in[3];
  const float* gn1_b = (const float*)d_in[4];
  const float* w_id = (const float*)d_in[5];
  const float* gnid_g = (const float*)d_in[6];
  const float* gnid_b = (const float*)d_in[7];
  const float* wq = (const float*)d_in[8];
  const float* wk = (const float*)d_in[9];
  const float* wv = (const float*)d_in[10];
  const float* wg1 = (const float*)d_in[11];
  const float* gng_g = (const float*)d_in[12];
  const float* gng_b = (const float*)d_in[13];
  const float* wg2 = (const float*)d_in[14];
  const float* bg2 = (const float*)d_in[15];
  const float* lnx1_g = (const float*)d_in[16];
  const float* lnx1_b = (const float*)d_in[17];
  const float* lnx2_g = (const float*)d_in[18];
  const float* lnx2_b = (const float*)d_in[19];
  const float* lno_g = (const float*)d_in[20];
  const float* lno_b = (const float*)d_in[21];
  const float* wh1 = (const float*)d_in[22];
  const float* gnh_g = (const float*)d_in[23];
  const float* gnh_b = (const float*)d_in[24];
  const float* wh2 = (const float*)d_in[25];
  const float* bh2 = (const float*)d_in[26];
  (void)in_sizes; (void)n_in; (void)out_size; (void)ws_size;

  float* ws = (float*)d_ws;
  float* c1 = ws;                              // 1310720
  float* xid = c1 + 1310720;                   // 1310720
  float* cg1 = xid + 1310720;                  // 655360
  float* ch1 = cg1 + 655360;                   // 1310720
  ushort* part_o = (ushort*)(ch1 + 1310720);   // 512*8*2560 = 10485760 ushorts
  float* part_l = (float*)(part_o + 10485760); // 131072
  float* pst1 = part_l + 131072;               // 640
  float* pstid = pst1 + 640;
  float* pstg = pstid + 640;
  float* psth = pstg + 640;
  ushort* qb = (ushort*)(psth + 640);          // 1310720
  ushort* kb = qb + 1310720;                   // 1310720
  ushort* vt = kb + 1310720;                   // 1572864
  ushort* x1_tm = vt + 1572864;                // 1115136
  ushort* x2_tm = x1_tm + 1115136;             // 1393920
  ushort* ym_tm = x2_tm + 1393920;             // 1393920 (dedicated; no alias)
  ushort* wp1t = ym_tm + 1393920;              // 55296
  ushort* widt = wp1t + 55296;                 // 7680
  ushort* wg1t = widt + 7680;                  // 46080
  ushort* wh1t = wg1t + 46080;                 // 69120

  // 1: repack all weights + zero all pad borders
  setup_k<<<dim3(1151), 256, 0, stream>>>(w_p1, w_id, wg1, wh1, wp1t, widt, wg1t, wh1t,
                                          x1_tm, x2_tm, ym_tm);
  // 2: stage both inputs to padded token-major bf16
  stage2_k<<<dim3(64, BSZ, 2), 256, 0, stream>>>(x1, x2, x1_tm, x2_tm);
  // 3: three independent convs in one grid
  convA_k<<<dim3(512, 8), 64, 0, stream>>>(x1_tm, x2_tm, wp1t, widt, wg1t, c1, xid, cg1);
  // 4: GN partial stats for all three tensors
  gnA_k<<<dim3(BSZ * NGRP, 16, 3), 256, 0, stream>>>(c1, xid, cg1, pst1, pstid, pstg);
  // 5: token transforms (q | k+gated v^T)
  qkv_k<<<dim3(64, BSZ, 2), 512, 0, stream>>>(c1, x2, cg1, pst1, pstg, gn1_g, gn1_b, gng_g,
                                              gng_b, lnx1_g, lnx1_b, lnx2_g, lnx2_b, wq, wk,
                                              wv, wg2, bg2, qb, kb, vt);
  // 6: attention partials
  attn2_k<<<dim3(16, BSZ, SPLIT), 512, 0, stream>>>(qb, kb, vt, part_o, part_l);
  // 7: merge + residual + LN -> padded map
  post2_k<<<dim3(64, BSZ), 512, 0, stream>>>(part_o, part_l, xid, pstid, gnid_g, gnid_b,
                                             lno_g, lno_b, ym_tm);
  // 8: head conv
  convH_k<<<dim3(512, 3), 64, 0, stream>>>(ym_tm, wh1t, ch1);
  // 9: head GN stats
  gnH_k<<<dim3(BSZ * NGRP, 16), 256, 0, stream>>>(ch1, psth);
  // 10: head final + xmin
  final_k<<<dim3(64, BSZ), 512, 0, stream>>>(ch1, psth, gnh_g, gnh_b, wh2, bh2, x2,
                                             (float*)d_out);
}

// Round 9
// 111.042 us; speedup vs baseline: 1.7956x; 1.7956x over previous
//
#include <hip/hip_runtime.h>
#include <hip/hip_bf16.h>
#include <math.h>

#define BSZ 4
#define CK 80
#define CX1 64
#define CGT 40
#define HH 64
#define WWI 64
#define HWSZ 4096
#define NGRP 5
#define EPSV 1e-5f
#define SPLIT 8
#define KPB (HWSZ / SPLIT)  // 512 keys per block
#define NCH (KPB / 32)      // 16 chunks
#define PADHW 4356          // 66*66

typedef short bf16x8 __attribute__((ext_vector_type(8)));
typedef float f32x16 __attribute__((ext_vector_type(16)));
#define MFMA32(a, b, c) __builtin_amdgcn_mfma_f32_32x32x16_bf16(a, b, c, 0, 0, 0)

__device__ __forceinline__ float sigmoidf_(float x) { return 1.f / (1.f + __expf(-x)); }
__device__ __forceinline__ float siluf_(float x) { return x * sigmoidf_(x); }

__device__ __forceinline__ ushort f2bf(float x) {
  union { float f; uint u; } c;
  c.f = x;
  uint u = c.u;
  return (ushort)((u + 0x7FFFu + ((u >> 16) & 1u)) >> 16);
}
__device__ __forceinline__ uint pack2bf(float lo, float hi) {
  return (uint)f2bf(lo) | ((uint)f2bf(hi) << 16);
}
__device__ __forceinline__ float bf2f(ushort u) {
  union { uint u; float f; } c;
  c.u = ((uint)u) << 16;
  return c.f;
}
__device__ __forceinline__ bf16x8 as_bf8(uint4 v) {
  union { uint4 u; bf16x8 b; } c;
  c.u = v;
  return c.b;
}
__device__ __forceinline__ bf16x8 ldb8(const ushort* p) { return *(const bf16x8*)p; }

// ================= setup: weight repacks + pad-border zeroes, 1 launch ========
// segments:
//  [0,55296)        wp1t 80,64,9,96        [178176,211456) zero x1_tm (32 u/pos)
//  [55296,62976)    widt 80,80,1,96        [211456,253056) zero x2_tm (40 u/pos)
//  [62976,109056)   wg1t 40,80,9,64        [253056,294656) zero ym_tm (40 u/pos)
//  [109056,178176)  wh1t 80,80,9,96
//  [294656,302336)  wqt [96][80] bf16 (x 1/sqrt80)
//  [302336,310016)  wkt [96][80]
//  [310016,317696)  wvt [96][80]
//  [317696,322304)  wg2t [96][48] (pad ci>=40, co>=80 zero)
__device__ __forceinline__ void repack_one(const float* w, ushort* wt, int idx, int COUT,
                                           int CIN, int TAPS, int COP) {
  int tap = idx / (COP * CIN);
  int rem = idx - tap * COP * CIN;
  int co = rem / CIN, ci = rem - co * CIN;
  float v = (co < COUT) ? w[((size_t)co * CIN + ci) * TAPS + tap] : 0.f;
  wt[idx] = f2bf(v);
}
__device__ __forceinline__ void zero_one(ushort* buf, int u, int cin) {
  int nu = cin >> 1;
  int pid = u / nu, uoff = u - pid * nu;
  int b = pid / 260, pos = pid - b * 260;
  int h, w;
  if (pos < 66) { h = 0; w = pos; }
  else if (pos < 132) { h = 65; w = pos - 66; }
  else if (pos < 196) { h = pos - 131; w = 0; }
  else { h = pos - 195; w = 65; }
  ((uint*)(buf + (((size_t)b * PADHW) + h * 66 + w) * cin))[uoff] = 0;
}
__device__ __forceinline__ void repack_lin(const float* w, ushort* wt, int idx, int COUT,
                                           int CIN, float scale) {
  int co = idx / CIN, ci = idx - co * CIN;
  float v = (co < COUT) ? w[(size_t)co * CIN + ci] * scale : 0.f;
  wt[idx] = f2bf(v);
}
__global__ __launch_bounds__(256) void setup_k(const float* __restrict__ w_p1,
                                               const float* __restrict__ w_id,
                                               const float* __restrict__ wg1,
                                               const float* __restrict__ wh1,
                                               const float* __restrict__ wq,
                                               const float* __restrict__ wk,
                                               const float* __restrict__ wv,
                                               const float* __restrict__ wg2,
                                               ushort* wp1t, ushort* widt, ushort* wg1t,
                                               ushort* wh1t, ushort* wqt, ushort* wkt,
                                               ushort* wvt, ushort* wg2t, ushort* x1_tm,
                                               ushort* x2_tm, ushort* ym_tm) {
  int idx = blockIdx.x * 256 + threadIdx.x;
  if (idx < 55296) repack_one(w_p1, wp1t, idx, 80, 64, 9, 96);
  else if (idx < 62976) repack_one(w_id, widt, idx - 55296, 80, 80, 1, 96);
  else if (idx < 109056) repack_one(wg1, wg1t, idx - 62976, 40, 80, 9, 64);
  else if (idx < 178176) repack_one(wh1, wh1t, idx - 109056, 80, 80, 9, 96);
  else if (idx < 211456) zero_one(x1_tm, idx - 178176, CX1);
  else if (idx < 253056) zero_one(x2_tm, idx - 211456, CK);
  else if (idx < 294656) zero_one(ym_tm, idx - 253056, CK);
  else if (idx < 302336)
    repack_lin(wq, wqt, idx - 294656, 80, 80, 0.111803398874989485f);
  else if (idx < 310016) repack_lin(wk, wkt, idx - 302336, 80, 80, 1.f);
  else if (idx < 317696) repack_lin(wv, wvt, idx - 310016, 80, 80, 1.f);
  else if (idx < 322304) {
    int i2 = idx - 317696;
    int co = i2 / 48, ci = i2 - co * 48;
    float v = (co < 80 && ci < 40) ? wg2[(size_t)co * 40 + ci] : 0.f;
    wg2t[i2] = f2bf(v);
  }
}

// ================= stage: NCHW f32 -> padded token-major bf16, both inputs ===
template <int CIN>
__device__ __forceinline__ void stage_body(const float* __restrict__ in,
                                           ushort* __restrict__ xtm,
                                           float (*tile)[81]) {
  int h = blockIdx.x, b = blockIdx.y;
  int w = threadIdx.x & 63, cio = threadIdx.x >> 6;
  for (int ci = cio; ci < CIN; ci += 4)
    tile[w][ci] = in[((size_t)(b * CIN + ci)) * HWSZ + h * 64 + w];
  __syncthreads();
  const int PAIRS = CIN / 2;
  for (int idx = threadIdx.x; idx < 64 * PAIRS; idx += 256) {
    int wi = idx / PAIRS, cp = idx - wi * PAIRS;
    uint pk = pack2bf(tile[wi][2 * cp], tile[wi][2 * cp + 1]);
    *(uint*)(&xtm[(((size_t)b * PADHW) + (h + 1) * 66 + (wi + 1)) * CIN + 2 * cp]) = pk;
  }
}
__global__ __launch_bounds__(256) void stage2_k(const float* __restrict__ x1,
                                                const float* __restrict__ x2,
                                                ushort* __restrict__ x1_tm,
                                                ushort* __restrict__ x2_tm) {
  __shared__ float tile[64][81];
  if (blockIdx.z == 0) stage_body<CX1>(x1, x1_tm, tile);
  else stage_body<CK>(x2, x2_tm, tile);
}

// ================= implicit-GEMM MFMA conv body =================
template <int CIN, int COP, int TAPS, int COUT>
__device__ __forceinline__ void conv_body(const ushort* __restrict__ xtm,
                                          const ushort* __restrict__ wt,
                                          float* __restrict__ out, int tile, int nt,
                                          float* lds) {
  int lane = threadIdx.x;
  int half = lane >> 5, lq = lane & 31;
  int b = tile >> 7;
  int tstart = (tile & 127) * 32;
  int h = tstart >> 6, w0 = tstart & 63;
  int p0 = (h + 1) * 66 + (w0 + lq + 1);
  const ushort* xb = xtm + ((size_t)b * PADHW) * CIN;
  const ushort* wbase = wt + ((size_t)(nt * 32 + lq)) * CIN + half * 8;
  f32x16 acc;
#pragma unroll
  for (int i = 0; i < 16; ++i) acc[i] = 0.f;
#pragma unroll 3
  for (int tap = 0; tap < TAPS; ++tap) {
    int dtap = (TAPS == 1) ? 0 : ((tap / 3) - 1) * 66 + (tap % 3) - 1;
    const ushort* ap = xb + (size_t)(p0 + dtap) * CIN + half * 8;
    const ushort* wp = wbase + (size_t)tap * COP * CIN;
#pragma unroll
    for (int kc = 0; kc < CIN / 16; ++kc) {
      acc = MFMA32(ldb8(ap + kc * 16), ldb8(wp + kc * 16), acc);
    }
  }
#pragma unroll
  for (int r = 0; r < 16; ++r) {
    int m = (r & 3) + 8 * (r >> 2) + 4 * half;
    lds[m * 33 + lq] = acc[r];
  }
  __syncthreads();
#pragma unroll
  for (int i = 0; i < 16; ++i) {
    int idx = i * 64 + lane;
    int c2 = idx >> 5, m2 = idx & 31;
    int co = nt * 32 + c2;
    if (co < COUT) out[((size_t)b * COUT + co) * HWSZ + tstart + m2] = lds[m2 * 33 + c2];
  }
}

__global__ __launch_bounds__(64) void convA_k(const ushort* __restrict__ x1_tm,
                                              const ushort* __restrict__ x2_tm,
                                              const ushort* __restrict__ wp1t,
                                              const ushort* __restrict__ widt,
                                              const ushort* __restrict__ wg1t,
                                              float* __restrict__ c1,
                                              float* __restrict__ xid,
                                              float* __restrict__ cg1) {
  __shared__ float lds[32 * 33];
  int zy = blockIdx.y;
  if (zy < 3) conv_body<CX1, 96, 9, CK>(x1_tm, wp1t, c1, blockIdx.x, zy, lds);
  else if (zy < 6) conv_body<CK, 96, 1, CK>(x2_tm, widt, xid, blockIdx.x, zy - 3, lds);
  else conv_body<CK, 64, 9, CGT>(x2_tm, wg1t, cg1, blockIdx.x, zy - 6, lds);
}

__global__ __launch_bounds__(64) void convH_k(const ushort* __restrict__ ym_tm,
                                              const ushort* __restrict__ wh1t,
                                              float* __restrict__ ch1) {
  __shared__ float lds[32 * 33];
  conv_body<CK, 96, 9, CK>(ym_tm, wh1t, ch1, blockIdx.x, blockIdx.y, lds);
}

// ================= GroupNorm partial sums =================
__device__ __forceinline__ void gn_part_body(const float* __restrict__ x,
                                             float* __restrict__ pstat, int C, int cpg) {
  int bg = blockIdx.x;
  int sl = blockIdx.y;
  int g = bg % NGRP, b = bg / NGRP;
  int npb = cpg * HWSZ / 16;
  const float4* p =
      (const float4*)(x + ((size_t)b * C + (size_t)g * cpg) * HWSZ + (size_t)sl * npb);
  int n4 = npb / 4;
  float s = 0.f, s2 = 0.f;
  for (int i = threadIdx.x; i < n4; i += 256) {
    float4 v = p[i];
    s += v.x + v.y + v.z + v.w;
    s2 += v.x * v.x + v.y * v.y + v.z * v.z + v.w * v.w;
  }
#pragma unroll
  for (int off = 32; off; off >>= 1) {
    s += __shfl_down(s, off);
    s2 += __shfl_down(s2, off);
  }
  __shared__ float sh[4][2];
  int wave = threadIdx.x >> 6;
  if ((threadIdx.x & 63) == 0) {
    sh[wave][0] = s;
    sh[wave][1] = s2;
  }
  __syncthreads();
  if (threadIdx.x == 0) {
    pstat[bg * 32 + sl * 2] = sh[0][0] + sh[1][0] + sh[2][0] + sh[3][0];
    pstat[bg * 32 + sl * 2 + 1] = sh[0][1] + sh[1][1] + sh[2][1] + sh[3][1];
  }
}
__global__ __launch_bounds__(256) void gnA_k(const float* __restrict__ c1,
                                             const float* __restrict__ xid,
                                             const float* __restrict__ cg1,
                                             float* __restrict__ pst1,
                                             float* __restrict__ pstid,
                                             float* __restrict__ pstg) {
  int z = blockIdx.z;
  if (z == 0) gn_part_body(c1, pst1, CK, 16);
  else if (z == 1) gn_part_body(xid, pstid, CK, 16);
  else gn_part_body(cg1, pstg, CGT, 8);
}
__global__ __launch_bounds__(256) void gnH_k(const float* __restrict__ ch1,
                                             float* __restrict__ psth) {
  gn_part_body(ch1, psth, CK, 16);
}

__device__ __forceinline__ void gn_fin_lds(const float* __restrict__ ps, int b, float invn,
                                           int tid, float* gsm, float* gsr) {
  if (tid < NGRP) {
    const float* p = ps + ((size_t)(b * NGRP + tid)) * 32;
    float s = 0.f, s2 = 0.f;
#pragma unroll
    for (int sl = 0; sl < 16; ++sl) {
      s += p[sl * 2];
      s2 += p[sl * 2 + 1];
    }
    float m = s * invn;
    gsm[tid] = m;
    gsr[tid] = rsqrtf(fmaxf(s2 * invn - m * m, 0.f) + EPSV);
  }
}

// ================= norm: produce bf16 GEMM inputs =================
// z=0: x1n = LN(SiLU(GN(c1)))   z=1: x2n = LN(x2)   z=2: gsi = SiLU(GN(cg1)) pad48
__global__ __launch_bounds__(512) void norm_k(const float* __restrict__ c1,
                                              const float* __restrict__ x2,
                                              const float* __restrict__ cg1,
                                              const float* __restrict__ pst1,
                                              const float* __restrict__ pstg,
                                              const float* __restrict__ gn1_g,
                                              const float* __restrict__ gn1_b,
                                              const float* __restrict__ gng_g,
                                              const float* __restrict__ gng_b,
                                              const float* __restrict__ lnx1_g,
                                              const float* __restrict__ lnx1_b,
                                              const float* __restrict__ lnx2_g,
                                              const float* __restrict__ lnx2_b,
                                              ushort* __restrict__ x1n,
                                              ushort* __restrict__ x2n,
                                              ushort* __restrict__ gsi) {
  __shared__ float xs[64][85];
  __shared__ float mrs[64][2];
  __shared__ float gsm[NGRP], gsr[NGRP];
  int tid = threadIdx.x, tl = tid & 63, g = tid >> 6;
  int b = blockIdx.y, n0 = blockIdx.x * 64;
  int z = blockIdx.z;

  if (z == 2) {
    gn_fin_lds(pstg, b, 1.f / (8 * HWSZ), tid, gsm, gsr);
    __syncthreads();
    ushort* gp = gsi + ((size_t)(b * HWSZ) + n0 + tl) * 48;
#pragma unroll
    for (int j = 0; j < 6; j += 2) {
      int c = g * 6 + j;
      float v0 = 0.f, v1 = 0.f;
      if (c < CGT) {
        int gr = c >> 3;
        v0 = siluf_((cg1[((size_t)(b * CGT + c)) * HWSZ + n0 + tl] - gsm[gr]) * gsr[gr] *
                        gng_g[c] +
                    gng_b[c]);
      }
      if (c + 1 < CGT) {
        int gr = (c + 1) >> 3;
        v1 = siluf_((cg1[((size_t)(b * CGT + c + 1)) * HWSZ + n0 + tl] - gsm[gr]) *
                        gsr[gr] * gng_g[c + 1] +
                    gng_b[c + 1]);
      }
      *(uint*)(gp + c) = pack2bf(v0, v1);
    }
    return;
  }

  if (z == 0) {
    gn_fin_lds(pst1, b, 1.f / (16 * HWSZ), tid, gsm, gsr);
    __syncthreads();
#pragma unroll
    for (int j = 0; j < 10; ++j) {
      int c = g * 10 + j;
      int gr = c >> 4;
      float v = (c1[((size_t)(b * CK + c)) * HWSZ + n0 + tl] - gsm[gr]) * gsr[gr] *
                    gn1_g[c] +
                gn1_b[c];
      xs[tl][c] = siluf_(v);
    }
  } else {
#pragma unroll
    for (int j = 0; j < 10; ++j) {
      int c = g * 10 + j;
      xs[tl][c] = x2[((size_t)(b * CK + c)) * HWSZ + n0 + tl];
    }
  }
  __syncthreads();
  if (tid < 64) {
    float s = 0.f, s2 = 0.f;
#pragma unroll
    for (int c = 0; c < CK; ++c) {
      float v = xs[tid][c];
      s += v;
      s2 += v * v;
    }
    float mean = s * (1.f / CK);
    float var = s2 * (1.f / CK) - mean * mean;
    mrs[tid][0] = mean;
    mrs[tid][1] = rsqrtf(var + EPSV);
  }
  __syncthreads();
  float mean = mrs[tl][0], rstd = mrs[tl][1];
  const float* lg = (z == 0) ? lnx1_g : lnx2_g;
  const float* lb = (z == 0) ? lnx1_b : lnx2_b;
  ushort* op = ((z == 0) ? x1n : x2n) + ((size_t)(b * HWSZ) + n0 + tl) * CK;
#pragma unroll
  for (int j = 0; j < 10; j += 2) {
    int c = g * 10 + j;
    float v0 = (xs[tl][c] - mean) * rstd * lg[c] + lb[c];
    float v1 = (xs[tl][c + 1] - mean) * rstd * lg[c + 1] + lb[c + 1];
    *(uint*)(op + c) = pack2bf(v0, v1);
  }
}

// ================= qkvg: MFMA GEMMs for q, k, gated-v =================
// grid (512, 9): zy/3 = segment {q, k, v+gate}, zy%3 = nt (32-out tile)
__global__ __launch_bounds__(64) void qkvg_k(const ushort* __restrict__ x1n,
                                             const ushort* __restrict__ x2n,
                                             const ushort* __restrict__ gsi,
                                             const ushort* __restrict__ wqt,
                                             const ushort* __restrict__ wkt,
                                             const ushort* __restrict__ wvt,
                                             const ushort* __restrict__ wg2t,
                                             const float* __restrict__ bg2,
                                             ushort* __restrict__ qb,
                                             ushort* __restrict__ kb,
                                             ushort* __restrict__ vt) {
  __shared__ float lds[32 * 33];
  int lane = threadIdx.x;
  int half = lane >> 5, lq = lane & 31;
  int tile = blockIdx.x, zy = blockIdx.y;
  int seg = zy / 3, nt = zy - seg * 3;
  int b = tile >> 7;
  int tstart = (tile & 127) * 32;

  if (seg < 2) {
    const ushort* xn = (seg == 0) ? x1n : x2n;
    const ushort* wt = (seg == 0) ? wqt : wkt;
    ushort* outb = (seg == 0) ? qb : kb;
    const ushort* ap = xn + ((size_t)(b * HWSZ) + tstart + lq) * CK + half * 8;
    const ushort* wp = wt + (size_t)(nt * 32 + lq) * CK + half * 8;
    f32x16 acc;
#pragma unroll
    for (int i = 0; i < 16; ++i) acc[i] = 0.f;
#pragma unroll
    for (int kc = 0; kc < 5; ++kc)
      acc = MFMA32(ldb8(ap + kc * 16), ldb8(wp + kc * 16), acc);
#pragma unroll
    for (int r = 0; r < 16; ++r) {
      int m = (r & 3) + 8 * (r >> 2) + 4 * half;
      lds[m * 33 + lq] = acc[r];
    }
    __syncthreads();
    // token-major bf16 write: 32 tokens x 16 channel-pairs
#pragma unroll
    for (int i = 0; i < 8; ++i) {
      int idx = i * 64 + lane;
      int tok = idx >> 4, pr = idx & 15;
      int co = nt * 32 + pr * 2;
      if (co < CK) {
        uint pk = pack2bf(lds[tok * 33 + pr * 2], lds[tok * 33 + pr * 2 + 1]);
        *(uint*)(&outb[((size_t)(b * HWSZ) + tstart + tok) * CK + co]) = pk;
      }
    }
  } else {
    const ushort* ap = x2n + ((size_t)(b * HWSZ) + tstart + lq) * CK + half * 8;
    const ushort* gp = gsi + ((size_t)(b * HWSZ) + tstart + lq) * 48 + half * 8;
    const ushort* wvp = wvt + (size_t)(nt * 32 + lq) * CK + half * 8;
    const ushort* wgp = wg2t + (size_t)(nt * 32 + lq) * 48 + half * 8;
    f32x16 vacc, gacc;
#pragma unroll
    for (int i = 0; i < 16; ++i) { vacc[i] = 0.f; gacc[i] = 0.f; }
#pragma unroll
    for (int kc = 0; kc < 5; ++kc)
      vacc = MFMA32(ldb8(ap + kc * 16), ldb8(wvp + kc * 16), vacc);
#pragma unroll
    for (int kc = 0; kc < 3; ++kc)
      gacc = MFMA32(ldb8(gp + kc * 16), ldb8(wgp + kc * 16), gacc);
    int co = nt * 32 + lq;
    float bias = (co < CK) ? bg2[co] : 0.f;
#pragma unroll
    for (int r = 0; r < 16; ++r) {
      int m = (r & 3) + 8 * (r >> 2) + 4 * half;
      float gv = 1.f + 0.1f * sigmoidf_(gacc[r] + bias);
      lds[m * 33 + lq] = vacc[r] * gv;
    }
    __syncthreads();
#pragma unroll
    for (int i = 0; i < 16; ++i) {
      int idx = i * 64 + lane;
      int c2 = idx >> 5, m2 = idx & 31;
      int co2 = nt * 32 + c2;
      vt[((size_t)(b * 96 + co2)) * HWSZ + tstart + m2] = f2bf(lds[m2 * 33 + c2]);
    }
  }
}

// ================= MFMA attention: 8 waves, async-split staging, bf16 partials =========
__global__ __launch_bounds__(512) void attn2_k(const ushort* __restrict__ qb,
                                               const ushort* __restrict__ kb,
                                               const ushort* __restrict__ vt,
                                               ushort* __restrict__ part_o,
                                               float* __restrict__ part_l) {
  __shared__ ushort kl[2][2816];  // 32 tok x 88ch(pad)
  __shared__ ushort vl[2][3456];  // 96 d x 36keys(pad)
  int tid = threadIdx.x, wid = tid >> 6, lane = tid & 63;
  int half = lane >> 5, lq = lane & 31;
  int qblk = blockIdx.x, b = blockIdx.y, ks = blockIdx.z;
  int k00 = ks * KPB;

  const ushort* qp =
      qb + ((size_t)b * HWSZ + qblk * 256 + wid * 32 + lq) * CK + half * 8;
  bf16x8 qf0 = *(const bf16x8*)(qp);
  bf16x8 qf1 = *(const bf16x8*)(qp + 16);
  bf16x8 qf2 = *(const bf16x8*)(qp + 32);
  bf16x8 qf3 = *(const bf16x8*)(qp + 48);
  bf16x8 qf4 = *(const bf16x8*)(qp + 64);

  f32x16 oa[3];
#pragma unroll
  for (int dt = 0; dt < 3; ++dt)
#pragma unroll
    for (int i = 0; i < 16; ++i) oa[dt][i] = 0.f;
  float lsum = 0.f;

  const ushort* kgb = kb + (size_t)b * HWSZ * CK;
  const ushort* vgb = vt + (size_t)b * 96 * HWSZ;

  uint4 kreg;
  uint2 vreg0, vreg1;
  int ktok = tid / 10, kgc = tid - ktok * 10;  // tid<320 only
  int vr0 = tid >> 3, vgc0 = tid & 7;
  int vr1 = (512 + tid) >> 3, vgc1 = tid & 7;

  auto load_stage = [&](int ch) {
    int k0 = k00 + ch * 32;
    const ushort* kg = kgb + (size_t)k0 * CK;
    if (tid < 320) kreg = *(const uint4*)(kg + (size_t)ktok * CK + kgc * 8);
    vreg0 = *(const uint2*)(vgb + (size_t)vr0 * HWSZ + k0 + vgc0 * 4);
    if (tid < 256) vreg1 = *(const uint2*)(vgb + (size_t)vr1 * HWSZ + k0 + vgc1 * 4);
  };
  auto write_stage = [&](int buf) {
    if (tid < 320) *(uint4*)(&kl[buf][ktok * 88 + kgc * 8]) = kreg;
    *(uint2*)(&vl[buf][vr0 * 36 + vgc0 * 4]) = vreg0;
    if (tid < 256) *(uint2*)(&vl[buf][vr1 * 36 + vgc1 * 4]) = vreg1;
  };

  load_stage(0);
  write_stage(0);
  __syncthreads();

  for (int c = 0; c < NCH; ++c) {
    int cur = c & 1;
    if (c + 1 < NCH) load_stage(c + 1);

    const ushort* klp = &kl[cur][lq * 88 + half * 8];
    f32x16 s;
#pragma unroll
    for (int i = 0; i < 16; ++i) s[i] = 0.f;
    s = MFMA32(*(const bf16x8*)(klp), qf0, s);
    s = MFMA32(*(const bf16x8*)(klp + 16), qf1, s);
    s = MFMA32(*(const bf16x8*)(klp + 32), qf2, s);
    s = MFMA32(*(const bf16x8*)(klp + 48), qf3, s);
    s = MFMA32(*(const bf16x8*)(klp + 64), qf4, s);

    uint w[8];
#pragma unroll
    for (int i = 0; i < 8; ++i) {
      float e0 = __expf(s[2 * i]);
      float e1 = __expf(s[2 * i + 1]);
      lsum += e0 + e1;
      __hip_bfloat162 t = __float22bfloat162_rn(make_float2(e0, e1));
      union { __hip_bfloat162 h; uint u; } cv;
      cv.h = t;
      w[i] = cv.u;
    }
    uint4 pw0 = make_uint4(w[0], w[1], w[2], w[3]);
    uint4 pw1 = make_uint4(w[4], w[5], w[6], w[7]);

#pragma unroll
    for (int dt = 0; dt < 3; ++dt) {
      const ushort* vp = &vl[cur][(dt * 32 + lq) * 36 + half * 4];
      uint2 a0 = *(const uint2*)(vp);
      uint2 b0 = *(const uint2*)(vp + 8);
      uint2 a1 = *(const uint2*)(vp + 16);
      uint2 b1 = *(const uint2*)(vp + 24);
      oa[dt] = MFMA32(as_bf8(make_uint4(a0.x, a0.y, b0.x, b0.y)), as_bf8(pw0), oa[dt]);
      oa[dt] = MFMA32(as_bf8(make_uint4(a1.x, a1.y, b1.x, b1.y)), as_bf8(pw1), oa[dt]);
    }
    if (c + 1 < NCH) write_stage(cur ^ 1);
    __syncthreads();
  }

  float ltot = lsum + __shfl_xor(lsum, 32);
  size_t tileidx = (size_t)((b * 128 + qblk * 8 + wid) * SPLIT + ks);
  ushort* po = part_o + tileidx * 2560;
#pragma unroll
  for (int dt = 0; dt < 3; ++dt)
#pragma unroll
    for (int r = 0; r < 16; ++r) {
      int d = dt * 32 + (r & 3) + 8 * (r >> 2) + 4 * half;
      if (d < CK) po[d * 32 + lq] = f2bf(oa[dt][r]);
    }
  if (lane < 32) part_l[tileidx * 32 + lq] = ltot;
}

// ================= post2: merge partials + residual GN + LN -> padded bf16 map =========
__global__ __launch_bounds__(512) void post2_k(const ushort* __restrict__ part_o,
                                               const float* __restrict__ part_l,
                                               const float* __restrict__ xid,
                                               const float* __restrict__ pstid,
                                               const float* __restrict__ gg,
                                               const float* __restrict__ gb,
                                               const float* __restrict__ lg,
                                               const float* __restrict__ lb,
                                               ushort* __restrict__ ym_tm) {
  __shared__ float xs[64][85];
  __shared__ float mrs[64][2];
  __shared__ float gsm[NGRP], gsr[NGRP];
  __shared__ float invl[64];
  int tid = threadIdx.x, tl = tid & 63, g = tid >> 6;
  int b = blockIdx.y, n0 = blockIdx.x * 64;
  gn_fin_lds(pstid, b, 1.f / (16 * HWSZ), tid, gsm, gsr);
  if (tid < 64) {
    int token = n0 + tid;
    int qt = token >> 5, lqq = token & 31;
    size_t tb = (size_t)(b * 128 + qt) * SPLIT;
    float s = 0.f;
#pragma unroll
    for (int sp = 0; sp < SPLIT; ++sp) s += part_l[(tb + sp) * 32 + lqq];
    invl[tid] = 1.f / s;
  }
  __syncthreads();
  {
    int token = n0 + tl;
    int qt = token >> 5, lqq = token & 31;
    size_t tb = (size_t)(b * 128 + qt) * SPLIT;
    float il = invl[tl];
#pragma unroll
    for (int j = 0; j < 10; ++j) {
      int c = g * 10 + j;
      int gr = c >> 4;
      float y = 0.f;
#pragma unroll
      for (int sp = 0; sp < SPLIT; ++sp)
        y += bf2f(part_o[(tb + sp) * 2560 + c * 32 + lqq]);
      y *= il;
      xs[tl][c] = y + ((xid[((size_t)(b * CK + c)) * HWSZ + n0 + tl] - gsm[gr]) * gsr[gr] *
                           gg[c] +
                       gb[c]);
    }
  }
  __syncthreads();
  if (tid < 64) {
    float s = 0.f, s2 = 0.f;
#pragma unroll
    for (int c = 0; c < CK; ++c) {
      float v = xs[tid][c];
      s += v;
      s2 += v * v;
    }
    float mean = s * (1.f / CK);
    float var = s2 * (1.f / CK) - mean * mean;
    mrs[tid][0] = mean;
    mrs[tid][1] = rsqrtf(var + EPSV);
  }
  __syncthreads();
  float mean = mrs[tl][0], rstd = mrs[tl][1];
#pragma unroll
  for (int j = 0; j < 10; ++j) {
    int c = g * 10 + j;
    xs[tl][c] = (xs[tl][c] - mean) * rstd * lg[c] + lb[c];
  }
  __syncthreads();
  int hh = n0 >> 6;
  ushort* op = ym_tm + (((size_t)b * PADHW) + (hh + 1) * 66 + 1) * CK;
  for (int idx = tid; idx < 640; idx += 512) {
    int w = idx / 10, q4 = idx - w * 10;
    const float* xp = &xs[w][q4 * 8];
    uint4 pk;
    pk.x = pack2bf(xp[0], xp[1]);
    pk.y = pack2bf(xp[2], xp[3]);
    pk.z = pack2bf(xp[4], xp[5]);
    pk.w = pack2bf(xp[6], xp[7]);
    *(uint4*)(op + (size_t)w * CK + q4 * 8) = pk;
  }
}

// ================= head final =================
__global__ __launch_bounds__(512) void final_k(const float* __restrict__ ch1,
                                               const float* __restrict__ psth,
                                               const float* __restrict__ gg,
                                               const float* __restrict__ gb,
                                               const float* __restrict__ wh2,
                                               const float* __restrict__ bh2,
                                               const float* __restrict__ x2,
                                               float* __restrict__ out) {
  __shared__ float pd[64][9];
  __shared__ float pm[64][9];
  __shared__ float gsm[NGRP], gsr[NGRP];
  int tid = threadIdx.x, tl = tid & 63, g = tid >> 6;
  int b = blockIdx.y, n0 = blockIdx.x * 64;
  gn_fin_lds(psth, b, 1.f / (16 * HWSZ), tid, gsm, gsr);
  __syncthreads();
  float acc = 0.f, mn = 3.4e38f;
#pragma unroll
  for (int j = 0; j < 10; ++j) {
    int c = g * 10 + j;
    int gr = c >> 4;
    float v = (ch1[((size_t)(b * CK + c)) * HWSZ + n0 + tl] - gsm[gr]) * gsr[gr] * gg[c] +
              gb[c];
    acc += siluf_(v) * wh2[c];
    mn = fminf(mn, x2[((size_t)(b * CK + c)) * HWSZ + n0 + tl]);
  }
  pd[tl][g] = acc;
  pm[tl][g] = mn;
  __syncthreads();
  if (tid < 64) {
    float a = bh2[0];
    float m = pm[tid][0];
#pragma unroll
    for (int g2 = 0; g2 < 8; ++g2) a += pd[tid][g2];
#pragma unroll
    for (int g2 = 1; g2 < 8; ++g2) m = fminf(m, pm[tid][g2]);
    out[(size_t)b * HWSZ + n0 + tid] = sigmoidf_(a);
    out[(size_t)BSZ * HWSZ + (size_t)b * HWSZ + n0 + tid] = m;
  }
}

extern "C" void kernel_launch(void* const* d_in, const int* in_sizes, int n_in,
                              void* d_out, int out_size, void* d_ws, size_t ws_size,
                              hipStream_t stream) {
  const float* x1 = (const float*)d_in[0];
  const float* x2 = (const float*)d_in[1];
  const float* w_p1 = (const float*)d_in[2];
  const float* gn1_g = (const float*)d_in[3];
  const float* gn1_b = (const float*)d_in[4];
  const float* w_id = (const float*)d_in[5];
  const float* gnid_g = (const float*)d_in[6];
  const float* gnid_b = (const float*)d_in[7];
  const float* wq = (const float*)d_in[8];
  const float* wk = (const float*)d_in[9];
  const float* wv = (const float*)d_in[10];
  const float* wg1 = (const float*)d_in[11];
  const float* gng_g = (const float*)d_in[12];
  const float* gng_b = (const float*)d_in[13];
  const float* wg2 = (const float*)d_in[14];
  const float* bg2 = (const float*)d_in[15];
  const float* lnx1_g = (const float*)d_in[16];
  const float* lnx1_b = (const float*)d_in[17];
  const float* lnx2_g = (const float*)d_in[18];
  const float* lnx2_b = (const float*)d_in[19];
  const float* lno_g = (const float*)d_in[20];
  const float* lno_b = (const float*)d_in[21];
  const float* wh1 = (const float*)d_in[22];
  const float* gnh_g = (const float*)d_in[23];
  const float* gnh_b = (const float*)d_in[24];
  const float* wh2 = (const float*)d_in[25];
  const float* bh2 = (const float*)d_in[26];
  (void)in_sizes; (void)n_in; (void)out_size; (void)ws_size;

  float* ws = (float*)d_ws;
  float* c1 = ws;                              // 1310720
  float* xid = c1 + 1310720;                   // 1310720
  float* cg1 = xid + 1310720;                  // 655360
  float* ch1 = cg1 + 655360;                   // 1310720
  ushort* part_o = (ushort*)(ch1 + 1310720);   // 10485760 ushorts
  float* part_l = (float*)(part_o + 10485760); // 131072
  float* pst1 = part_l + 131072;               // 640
  float* pstid = pst1 + 640;
  float* pstg = pstid + 640;
  float* psth = pstg + 640;
  ushort* qb = (ushort*)(psth + 640);          // 1310720
  ushort* kb = qb + 1310720;                   // 1310720
  ushort* vt = kb + 1310720;                   // 1572864
  ushort* x1_tm = vt + 1572864;                // 1115136
  ushort* x2_tm = x1_tm + 1115136;             // 1393920
  ushort* ym_tm = x2_tm + 1393920;             // 1393920
  ushort* x1n = ym_tm + 1393920;               // 1310720
  ushort* x2n = x1n + 1310720;                 // 1310720
  ushort* gsi = x2n + 1310720;                 // 786432
  ushort* wp1t = gsi + 786432;                 // 55296
  ushort* widt = wp1t + 55296;                 // 7680
  ushort* wg1t = widt + 7680;                  // 46080
  ushort* wh1t = wg1t + 46080;                 // 69120
  ushort* wqt = wh1t + 69120;                  // 7680
  ushort* wkt = wqt + 7680;                    // 7680
  ushort* wvt = wkt + 7680;                    // 7680
  ushort* wg2t = wvt + 7680;                   // 4608

  // 1: repack all weights + zero all pad borders
  setup_k<<<dim3(1259), 256, 0, stream>>>(w_p1, w_id, wg1, wh1, wq, wk, wv, wg2, wp1t,
                                          widt, wg1t, wh1t, wqt, wkt, wvt, wg2t, x1_tm,
                                          x2_tm, ym_tm);
  // 2: stage both inputs
  stage2_k<<<dim3(64, BSZ, 2), 256, 0, stream>>>(x1, x2, x1_tm, x2_tm);
  // 3: three input convs
  convA_k<<<dim3(512, 8), 64, 0, stream>>>(x1_tm, x2_tm, wp1t, widt, wg1t, c1, xid, cg1);
  // 4: GN stats
  gnA_k<<<dim3(BSZ * NGRP, 16, 3), 256, 0, stream>>>(c1, xid, cg1, pst1, pstid, pstg);
  // 5: norms -> bf16 GEMM inputs
  norm_k<<<dim3(64, BSZ, 3), 512, 0, stream>>>(c1, x2, cg1, pst1, pstg, gn1_g, gn1_b,
                                               gng_g, gng_b, lnx1_g, lnx1_b, lnx2_g,
                                               lnx2_b, x1n, x2n, gsi);
  // 6: q/k/gated-v MFMA GEMMs
  qkvg_k<<<dim3(512, 9), 64, 0, stream>>>(x1n, x2n, gsi, wqt, wkt, wvt, wg2t, bg2, qb, kb,
                                          vt);
  // 7: attention partials
  attn2_k<<<dim3(16, BSZ, SPLIT), 512, 0, stream>>>(qb, kb, vt, part_o, part_l);
  // 8: merge + residual + LN -> padded map
  post2_k<<<dim3(64, BSZ), 512, 0, stream>>>(part_o, part_l, xid, pstid, gnid_g, gnid_b,
                                             lno_g, lno_b, ym_tm);
  // 9: head conv
  convH_k<<<dim3(512, 3), 64, 0, stream>>>(ym_tm, wh1t, ch1);
  // 10: head GN stats
  gnH_k<<<dim3(BSZ * NGRP, 16), 256, 0, stream>>>(ch1, psth);
  // 11: head final + xmin
  final_k<<<dim3(64, BSZ), 512, 0, stream>>>(ch1, psth, gnh_g, gnh_b, wh2, bh2, x2,
                                             (float*)d_out);
}